// Round 7
// baseline (299.221 us; speedup 1.0000x reference)
//
#include <hip/hip_runtime.h>

// LSTM B=4096, S=512, INPUT=1, HIDDEN=20 + linear head.
// R7 = R6 with the cvt_pkrtz type fix (__fp16 vector, bit_cast to u32).
// MFMA recurrence with lane-closed dataflow. One wave = 16 chains.
// v_mfma_f32_16x16x32_f16, 5 MFMAs per step cover the 80 gate-rows.
// Row order: MFMA m, row 4*q+r  <->  gate r of unit 4m+q   (q=lane>>4)
//   => lane (q, n=lane&15) gets all 4 gates of unit 4m+q, chain n, in D regs
//      of MFMA m: c-update is lane-local.
// K-column permutation: position k=8*qt+t <-> source unit 4t+qt (t=0..4)
//   => the 5 h values lane (q,n) computes (units {4m+q}) are exactly the
//      B-operand elements (B[k=8q+t][n], t=0..4) that SAME lane supplies
//      next step. ZERO cross-lane traffic, ZERO LDS in the recurrence.
// Weights: 5 A-frags (f16, 20 VGPRs), pre-scaled by -log2e (i,f,o) /
// -2log2e (g) so sigmoid = rcp(1+exp2(a)), tanh = 2*rcp(1+exp2(a))-1.
// x*W_ih + bias enters as fp32 MFMA C-init (no f16 bias error).
// Activations rcp-fused: 5 exp2 + 2 rcp per unit.
//   c' = [c*B*G + A*(2-G)] / (A*B*G);  h = (2-C)/(O*C)
// Head: per-step lane partial (5 fma) -> LDS transpose, gathered once per
// 16-step chunk (single wave per block: no barriers anywhere).
// 256 blocks x 64 threads = 1 wave per CU; issue-bound ~480 cyc/step.

#define BATCH 4096
#define SLEN  512
#define H     20
#define CHUNK 16
#define LOG2E 1.44269504088896340736f

typedef _Float16 v8h __attribute__((ext_vector_type(8)));
typedef float    f4  __attribute__((ext_vector_type(4)));

__device__ __forceinline__ float fexp2(float x) { return __builtin_amdgcn_exp2f(x); }
__device__ __forceinline__ float frcp(float x)  { return __builtin_amdgcn_rcpf(x); }
__device__ __forceinline__ unsigned int pkrtz(float a, float b) {
    return __builtin_bit_cast(unsigned int, __builtin_amdgcn_cvt_pkrtz(a, b));
}

__global__ __launch_bounds__(64, 1) void lstm_mfma(
    const float* __restrict__ x,      // [B, S, 1]
    const float* __restrict__ W_ih,   // [80, 1]
    const float* __restrict__ W_hh,   // [80, 20]
    const float* __restrict__ b_ih,   // [80]
    const float* __restrict__ b_hh,   // [80]
    const float* __restrict__ W_lin,  // [1, 20]
    const float* __restrict__ b_lin,  // [1]
    float* __restrict__ out)          // [B, S, 1]
{
    __shared__ __align__(16) float hd[CHUNK][16][4];  // head partials [i][n][q]

    const int lane = threadIdx.x;       // 0..63
    const int n    = lane & 15;         // chain column
    const int q    = lane >> 4;         // quad
    const int cb   = blockIdx.x * 16;   // chain base (256*16 = 4096 exact)

    const float s1 = -LOG2E;            // sigmoid pre-scale
    const float s2 = -2.0f * LOG2E;     // tanh pre-scale

    // ---- A fragments: A[row=lane&15][k=q*8+j], row -> (unit 4m+(row>>2), gate row&3),
    //      k=8q+j -> source unit 4j+q (j=0..4), j>=5 zero ----
    v8h af[5];
    {
        const int rA   = lane & 15;
        const int gate = rA & 3;
        const int ub   = rA >> 2;
        const float s  = (gate == 2) ? s2 : s1;
#pragma unroll
        for (int m = 0; m < 5; ++m) {
            const int ut = 4 * m + ub;          // target unit (row of W_hh block)
            v8h a;
#pragma unroll
            for (int j = 0; j < 8; ++j) a[j] = (_Float16)0.0f;
#pragma unroll
            for (int j = 0; j < 5; ++j)
                a[j] = (_Float16)(s * W_hh[(gate * H + ut) * H + (4 * j + q)]);
            af[m] = a;
        }
    }

    // ---- per-lane D-side constants: unit 4m+q, gates 0..3 (fp32) ----
    f4 xwv[5], bbv[5];
    float wl[5];
#pragma unroll
    for (int m = 0; m < 5; ++m) {
        const int ud = 4 * m + q;               // this lane's unit in D of MFMA m
#pragma unroll
        for (int r = 0; r < 4; ++r) {
            const float s  = (r == 2) ? s2 : s1;
            const int  idx = r * H + ud;
            xwv[m][r] = s * W_ih[idx];
            bbv[m][r] = s * (b_ih[idx] + b_hh[idx]);
        }
        wl[m] = W_lin[ud];
    }
    const float blin = b_lin[0];

    const float* xrow = x   + (long)(cb + n) * SLEN;
    float*       orow = out + (long)(cb + n) * SLEN;

    // recurrent state: c for units {4m+q} of chain n; B-frag = h(t-1) (zeros)
    float cc[5] = {0.0f, 0.0f, 0.0f, 0.0f, 0.0f};
    uint4 bz; bz.x = 0u; bz.y = 0u; bz.z = 0u; bz.w = 0u;
    v8h Bfrag = __builtin_bit_cast(v8h, bz);

#pragma unroll 1
    for (int T = 0; T < SLEN; T += CHUNK) {
        // x chunk for this chain (16 fp32, 4x dwordx4; q-duplicates hit L1)
        f4 xc[4];
#pragma unroll
        for (int k = 0; k < 4; ++k)
            xc[k] = *(const f4*)(xrow + T + 4 * k);

#pragma unroll
        for (int i = 0; i < CHUNK; ++i) {
            const float xt = xc[i >> 2][i & 3];
            // C-init (fp32): xg + bias for this lane's 4 gate rows per MFMA
            f4 d[5];
#pragma unroll
            for (int m = 0; m < 5; ++m) {
                f4 ci;
#pragma unroll
                for (int r = 0; r < 4; ++r)
                    ci[r] = fmaf(xt, xwv[m][r], bbv[m][r]);
                d[m] = __builtin_amdgcn_mfma_f32_16x16x32_f16(af[m], Bfrag, ci, 0, 0, 0);
            }
            // lane-local activations: d[m] = scaled pre-acts (i,f,g,o), unit 4m+q
            float hm[5];
#pragma unroll
            for (int m = 0; m < 5; ++m) {
                const float eI = fexp2(d[m][0]);
                const float eF = fexp2(d[m][1]);
                const float eG = fexp2(d[m][2]);
                const float eO = fexp2(d[m][3]);
                const float Bv = 1.0f + eI, Av = 1.0f + eF;
                const float Gv = 1.0f + eG, Ov = 1.0f + eO;
                const float P  = Bv * Gv;
                const float N  = fmaf(cc[m], P, Av * (2.0f - Gv));
                cc[m] = N * frcp(Av * P);
                const float eC = fexp2(s2 * cc[m]);
                const float Cv = 1.0f + eC;
                hm[m] = (2.0f - Cv) * frcp(Ov * Cv);
            }
            // next-step B fragment: elements j=0..4 = h of units {4j+q} = hm[j]
            {
                uint4 t;
                t.x = pkrtz(hm[0], hm[1]);
                t.y = pkrtz(hm[2], hm[3]);
                t.z = pkrtz(hm[4], 0.0f);
                t.w = 0u;
                Bfrag = __builtin_bit_cast(v8h, t);
            }
            // head partial for (chain n, step T+i): this lane's 5 units
            float p = hm[0] * wl[0];
            p = fmaf(hm[1], wl[1], p);
            p = fmaf(hm[2], wl[2], p);
            p = fmaf(hm[3], wl[3], p);
            p = fmaf(hm[4], wl[4], p);
            hd[i][n][q] = p;   // word n*4+q: 2-way bank alias = free
        }

        // ---- chunk-end head gather: lane (q,n) -> chain n, steps 4q..4q+3 ----
        {
            f4 y;
#pragma unroll
            for (int r = 0; r < 4; ++r) {
                const f4 v = *(const f4*)&hd[4 * q + r][n][0];
                y[r] = v[0] + v[1] + v[2] + v[3] + blin;
            }
            *(f4*)(orow + T + 4 * q) = y;   // coalesced dwordx4
        }
    }
}

extern "C" void kernel_launch(void* const* d_in, const int* in_sizes, int n_in,
                              void* d_out, int out_size, void* d_ws, size_t ws_size,
                              hipStream_t stream) {
    const float* x     = (const float*)d_in[0];
    const float* W_ih  = (const float*)d_in[1];
    const float* W_hh  = (const float*)d_in[2];
    const float* b_ih  = (const float*)d_in[3];
    const float* b_hh  = (const float*)d_in[4];
    const float* W_lin = (const float*)d_in[5];
    const float* b_lin = (const float*)d_in[6];
    float* out = (float*)d_out;

    lstm_mfma<<<BATCH / 16, 64, 0, stream>>>(x, W_ih, W_hh, b_ih, b_hh,
                                             W_lin, b_lin, out);
}

// Round 8
// 247.083 us; speedup vs baseline: 1.2110x; 1.2110x over previous
//
#include <hip/hip_runtime.h>

// LSTM B=4096, S=512, INPUT=1, HIDDEN=20 + linear head.
// R8 = R3 structure (3 chains per 64-lane wave, lane=(chain,unit), all 4
// gates per lane, fp16 dot2 gates, fp16 LDS h-ring, deferred head) with the
// transcendental pipe replaced by LDS lerp tables:
//   sigma/tanh over [-8,8], 1024 entries, float2 {y, dy}: one ds_read_b64 +
//   one fmaf per activation. Index transform (x*64+512) is FOLDED into the
//   pre-scaled weights/biases, so gate pre-acts arrive in index units.
// Per-activation cost ~18 cyc vs ~36+ for exp2/rcp; per wave-step issue
// ~210 cyc vs R3's ~500 (trans was 340 of it). Trans work now spread over
// all SIMDs as cheap VALU+LDS instead of quarter-rate trans ops.
// Tables built per block (single wave: no barrier needed; wave-internal
// lgkmcnt orders ds_write -> ds_read).

#define BATCH 4096
#define SLEN  512
#define H     20
#define CHUNK 16
#define LOG2E 1.44269504088896340736f
#define TSCALE 64.0f     // LUT entries per unit input
#define TOFF   512.0f    // LUT index offset (x=0 -> entry 512)
#define GSTRIDE 200      // words per group LDS h-region
#define RSTRIDE 12       // words per h row (10 half2 + 2 pad)

typedef _Float16 h2 __attribute__((ext_vector_type(2)));

__device__ __forceinline__ float fexp2(float x) { return __builtin_amdgcn_exp2f(x); }
__device__ __forceinline__ float frcp(float x)  { return __builtin_amdgcn_rcpf(x); }
__device__ __forceinline__ h2 bch2(unsigned int u) { return __builtin_bit_cast(h2, u); }

__device__ __forceinline__ float sigma_exact(float x) {
    return frcp(1.0f + fexp2(-LOG2E * x));
}

// lerp lookup: af already in index units (x*64+512)
__device__ __forceinline__ float lut(const float* T, float af) {
    const float u  = fminf(fmaxf(af, 0.0f), 1022.999f);  // med3
    const int   i  = (int)u;
    const float t  = u - (float)i;
    const float2 e = *(const float2*)&T[2 * i];           // ds_read_b64
    return fmaf(t, e.y, e.x);
}

__global__ __launch_bounds__(64, 4) void lstm_lut(
    const float* __restrict__ x,      // [B, S, 1]
    const float* __restrict__ W_ih,   // [80, 1]
    const float* __restrict__ W_hh,   // [80, 20]
    const float* __restrict__ b_ih,   // [80]
    const float* __restrict__ b_hh,   // [80]
    const float* __restrict__ W_lin,  // [1, 20]
    const float* __restrict__ b_lin,  // [1]
    float* __restrict__ out)          // [B, S, 1]
{
    __shared__ __align__(16) unsigned int hw[4 * GSTRIDE];  // h ring, fp16
    __shared__ float xbuf[4][CHUNK];
    __shared__ __align__(16) float Tsig[2048];   // 1024 x {y, dy}
    __shared__ __align__(16) float Ttan[2048];
    _Float16* hh = (_Float16*)hw;

    const int lane = threadIdx.x;           // 0..63
    int grp = lane / H;                     // 0..3 (3 = dummy group)
    const int j = lane - grp * H;           // 0..19 (0..3 for dummy)
    const long b = (long)blockIdx.x * 3 + grp;
    const bool valid = (grp < 3) && (b < BATCH);
    const long bc = valid ? b : 0;

    // ---- build lerp tables: sigma(x), tanh(x) on [-8,8), 1024 nodes ----
#pragma unroll
    for (int it = 0; it < 16; ++it) {
        const int   k  = it * 64 + lane;
        const float x0 = ((float)k - 512.0f) * (1.0f / 64.0f);
        const float x1 = x0 + (1.0f / 64.0f);
        const float s0 = sigma_exact(x0), s1 = sigma_exact(x1);
        const float t0 = fmaf(2.0f, sigma_exact(2.0f * x0), -1.0f);
        const float t1 = fmaf(2.0f, sigma_exact(2.0f * x1), -1.0f);
        Tsig[2 * k]     = s0;
        Tsig[2 * k + 1] = s1 - s0;
        Ttan[2 * k]     = t0;
        Ttan[2 * k + 1] = t1 - t0;
    }

    // ---- per-lane weights: 4 gate rows x 10 half2, scaled to INDEX units ----
    h2 w2[4][10];
    float bb[4], xw[4];
#pragma unroll
    for (int g = 0; g < 4; ++g) {
        const int row = g * H + j;
#pragma unroll
        for (int k = 0; k < 10; ++k) {
            h2 t;
            t.x = (_Float16)(TSCALE * W_hh[row * H + 2 * k]);
            t.y = (_Float16)(TSCALE * W_hh[row * H + 2 * k + 1]);
            w2[g][k] = t;
        }
        bb[g] = fmaf(TSCALE, b_ih[row] + b_hh[row], TOFF);  // fold +512
        xw[g] = TSCALE * W_ih[row];
    }
    h2 wl2[10];
#pragma unroll
    for (int k = 0; k < 10; ++k) {
        h2 t;
        t.x = (_Float16)W_lin[2 * k];
        t.y = (_Float16)W_lin[2 * k + 1];
        wl2[k] = t;
    }
    const float blin = b_lin[0];

    const float* xb = x + bc * SLEN;
    float*       ob = out + bc * SLEN;

    const int gbase = grp * GSTRIDE;
    hh[2 * (gbase + (CHUNK - 1) * RSTRIDE) + j] = (_Float16)0.0f;  // h(-1)=0
    float c = 0.0f;

#pragma unroll 1
    for (int T = 0; T < SLEN; T += CHUNK) {
        if (j < CHUNK) xbuf[grp][j] = xb[T + j];   // coalesced x chunk -> LDS

#pragma unroll
        for (int i = 0; i < CHUNK; ++i) {
            const int rp = (i + CHUNK - 1) & (CHUNK - 1);
            const int base = gbase + rp * RSTRIDE;
            const float xt = xbuf[grp][i];          // group broadcast
            // h(t-1) row: 20 fp16 = b128 + b128 + b64
            const uint4 A = *(const uint4*)&hw[base];
            const uint4 B = *(const uint4*)&hw[base + 4];
            const uint2 C = *(const uint2*)&hw[base + 8];
            const unsigned int pw[10] = {A.x, A.y, A.z, A.w,
                                         B.x, B.y, B.z, B.w, C.x, C.y};
            float a[4];
#pragma unroll
            for (int g = 0; g < 4; ++g) a[g] = fmaf(xt, xw[g], bb[g]);
#pragma unroll
            for (int k = 0; k < 10; ++k) {
#pragma unroll
                for (int g = 0; g < 4; ++g)   // 4 independent dep chains
                    a[g] = __builtin_amdgcn_fdot2(bch2(pw[k]), w2[g][k], a[g], false);
            }
            // activations via lerp tables (pre-acts already in index units)
            const float gi = lut(Tsig, a[0]);
            const float gf = lut(Tsig, a[1]);
            const float gg = lut(Ttan, a[2]);
            const float go = lut(Tsig, a[3]);
            c = fmaf(gf, c, gi * gg);
            const float tc = lut(Ttan, fmaf(c, TSCALE, TOFF));
            const float hval = go * tc;
            hh[2 * (gbase + i * RSTRIDE) + j] = (_Float16)hval;  // ds_write_b16
        }

        // ---- deferred head: lanes j<16 reduce one stored row each ----
        if (j < CHUNK) {
            const int rb = gbase + j * RSTRIDE;
            const uint4 A = *(const uint4*)&hw[rb];
            const uint4 B = *(const uint4*)&hw[rb + 4];
            const uint2 C = *(const uint2*)&hw[rb + 8];
            const unsigned int pw[10] = {A.x, A.y, A.z, A.w,
                                         B.x, B.y, B.z, B.w, C.x, C.y};
            float y = blin;
#pragma unroll
            for (int k = 0; k < 10; ++k)
                y = __builtin_amdgcn_fdot2(bch2(pw[k]), wl2[k], y, false);
            if (valid) ob[T + j] = y;   // coalesced 16-float burst per chain
        }
    }
}

extern "C" void kernel_launch(void* const* d_in, const int* in_sizes, int n_in,
                              void* d_out, int out_size, void* d_ws, size_t ws_size,
                              hipStream_t stream) {
    const float* x     = (const float*)d_in[0];
    const float* W_ih  = (const float*)d_in[1];
    const float* W_hh  = (const float*)d_in[2];
    const float* b_ih  = (const float*)d_in[3];
    const float* b_hh  = (const float*)d_in[4];
    const float* W_lin = (const float*)d_in[5];
    const float* b_lin = (const float*)d_in[6];
    float* out = (float*)d_out;

    const int nblocks = (BATCH + 2) / 3;  // 3 chains per 64-thread wave/block
    lstm_lut<<<nblocks, 64, 0, stream>>>(x, W_ih, W_hh, b_ih, b_hh,
                                         W_lin, b_lin, out);
}